// Round 3
// baseline (97.511 us; speedup 1.0000x reference)
//
#include <hip/hip_runtime.h>
#include <math.h>

#define H_IMG 1024
#define W_IMG 1280
#define NPIX (H_IMG * W_IMG)
#define TPB 256
// Vector region: pixels [3, 3 + 4*NV) handled as float4 groups so that stores
// to out+9+... land 16B-aligned (out+12, out+12+NPIX). NV = (NPIX-3)/4.
#define NV ((NPIX - 3) / 4)   // 327679

// ---------------------------------------------------------------------------
// jnp.linalg.pinv default rcond = 10*max(M,N)*eps(f32) ~= 1.56 here, so the
// singular-value cutoff exceeds sigma_max: pinv(J) == 0, x0 == 0, R == I for
// all 5 iterations. Outputs: R = I; warped = warp(ref, Hi(I));
// res = mask * (warped - target).
// ---------------------------------------------------------------------------

__device__ inline float tap(const float* __restrict__ img, int yi, int xi, float wt) {
    bool valid = (xi >= 0) & (xi < W_IMG) & (yi >= 0) & (yi < H_IMG);
    int yc = min(max(yi, 0), H_IMG - 1);
    int xc = min(max(xi, 0), W_IMG - 1);
    float v = img[yc * W_IMG + xc];
    return valid ? v * wt : 0.0f;
}

__device__ inline float warp_px(const float* __restrict__ ref, int p,
                                float h0, float h1, float h2,
                                float h3, float h4, float h5,
                                float h6, float h7, float h8) {
    float u = (float)(p % W_IMG);
    float v = (float)(p / W_IMG);
    float den = h6 * u + h7 * v + h8;
    float xs = (h0 * u + h1 * v + h2) / den;
    float ys = (h3 * u + h4 * v + h5) / den;
    float x0f = floorf(xs), y0f = floorf(ys);
    float wx = xs - x0f, wy = ys - y0f;
    int x0 = (int)x0f, y0 = (int)y0f;
    float acc = 0.0f;
    acc += tap(ref, y0,     x0,     (1.f - wx) * (1.f - wy));
    acc += tap(ref, y0,     x0 + 1, wx * (1.f - wy));
    acc += tap(ref, y0 + 1, x0,     (1.f - wx) * wy);
    acc += tap(ref, y0 + 1, x0 + 1, wx * wy);
    return acc;
}

__global__ __launch_bounds__(TPB) void k_all(const float* __restrict__ ref,
                                             const float* __restrict__ target,
                                             const float* __restrict__ mask,
                                             const float* __restrict__ K,
                                             float* __restrict__ out) {
    int t = blockIdx.x * TPB + threadIdx.x;
    if (t > NV) return;  // grid covers NV+1 threads (last one = cleanup lane)

    // ---- Hi = inv(K @ I @ inv(K)), mimicking the reference's f32 path ----
    float f  = K[0], cu = K[2];
    float f2 = K[4], cv = K[5];
    float Ki00 = 1.0f / f,  Ki02 = -cu / f;
    float Ki11 = 1.0f / f2, Ki12 = -cv / f2;
    float Hm0 = f * Ki00;
    float Hm2 = f * Ki02 + cu;
    float Hm4 = f2 * Ki11;
    float Hm5 = f2 * Ki12 + cv;
    double a = Hm0, c = Hm2, e = Hm4, g = Hm5;
    // adjugate inverse of [[a,0,c],[0,e,g],[0,0,1]] (double, like jnp.linalg.inv path)
    double C00 = e;
    double C11 = a;
    double C20 = -c * e;
    double C21 = -(a * g);
    double C22 = a * e;
    double det = a * C00;
    double inv = 1.0 / det;
    float h0 = (float)(C00 * inv), h1 = 0.0f, h2 = (float)(C20 * inv);
    float h3 = 0.0f, h4 = (float)(C11 * inv), h5 = (float)(C21 * inv);
    float h6 = 0.0f, h7 = 0.0f, h8 = (float)(C22 * inv);

    float* out_R    = out;             // 9
    float* out_res  = out + 9;         // NPIX
    float* out_warp = out + 9 + NPIX;  // NPIX

    if (t < NV) {
        int p0 = 3 + 4 * t;
        // aligned float4 loads covering target/mask[p0..p0+3] (p0 = 4t+3)
        const float4* tg4 = (const float4*)target;
        const float4* mk4 = (const float4*)mask;
        float4 tq0 = tg4[t], tq1 = tg4[t + 1];
        float4 mq0 = mk4[t], mq1 = mk4[t + 1];
        float tg[4] = {tq0.w, tq1.x, tq1.y, tq1.z};
        float mk[4] = {mq0.w, mq1.x, mq1.y, mq1.z};

        float w[4];
#pragma unroll
        for (int j = 0; j < 4; ++j)
            w[j] = warp_px(ref, p0 + j, h0, h1, h2, h3, h4, h5, h6, h7, h8);

        float4 wv = make_float4(w[0], w[1], w[2], w[3]);
        float4 rv = make_float4(mk[0] * (w[0] - tg[0]),
                                mk[1] * (w[1] - tg[1]),
                                mk[2] * (w[2] - tg[2]),
                                mk[3] * (w[3] - tg[3]));
        // out+12+4t and out+12+NPIX+4t are 16B-aligned
        *(float4*)(out_res + 3 + 4 * t)  = rv;
        *(float4*)(out_warp + 3 + 4 * t) = wv;
    } else {
        // cleanup lane: pixels 0,1,2 and NPIX-1
        const int px[4] = {0, 1, 2, NPIX - 1};
#pragma unroll
        for (int j = 0; j < 4; ++j) {
            int p = px[j];
            float wv = warp_px(ref, p, h0, h1, h2, h3, h4, h5, h6, h7, h8);
            out_warp[p] = wv;
            out_res[p]  = mask[p] * (wv - target[p]);
        }
    }

    if (t < 9) out_R[t] = ((t & 3) == 0) ? 1.0f : 0.0f;  // identity
}

extern "C" void kernel_launch(void* const* d_in, const int* in_sizes, int n_in,
                              void* d_out, int out_size, void* d_ws, size_t ws_size,
                              hipStream_t stream) {
    const float* ref_img = (const float*)d_in[0];
    const float* target  = (const float*)d_in[1];
    const float* mask    = (const float*)d_in[2];
    const float* K       = (const float*)d_in[3];
    // d_in[4] (batch_proj_jac) unused: pinv cutoff makes x0 == 0 identically.

    int nthreads = NV + 1;
    int nblocks = (nthreads + TPB - 1) / TPB;
    k_all<<<nblocks, TPB, 0, stream>>>(ref_img, target, mask, K, (float*)d_out);
}